// Round 1
// baseline (223.042 us; speedup 1.0000x reference)
//
#include <hip/hip_runtime.h>
#include <hip/hip_bf16.h>
#include <cstdint>
#include <cstddef>

// SupConLoss, N=16384 D=128, T=0.07, 100 classes.
// Strategy: bf16 MFMA on upper-triangular 128x128 tiles of the symmetric
// similarity matrix; fused exp/mask epilogue accumulating row sums (and
// column sums for the mirrored lower-triangular contribution); diagonal
// term exp(1/T) added analytically (dominant denom term -> fp32-exact).

#define N_ROWS 16384
#define DIM    128
#define TILE   128
#define NTILES (N_ROWS / TILE)   // 128

// exp(sim/T) = exp2( dot * log2(e)/T ); bake sqrt(log2(e)/T) into features.
// log2(e)/0.07 = 20.609929155556617 ; sqrt = 4.5398164
#define FEAT_SCALE 4.5398164f

typedef __attribute__((ext_vector_type(8))) short bf16x8;
typedef __attribute__((ext_vector_type(4))) float f32x4;

typedef const __attribute__((address_space(1))) unsigned int* gas_ptr;
typedef __attribute__((address_space(3))) unsigned int* las_ptr;

// ---------------------------------------------------------------- normalize
__global__ __launch_bounds__(256) void k_normalize(const float* __restrict__ F,
                                                   __hip_bfloat16* __restrict__ G) {
    int tid  = threadIdx.x;
    int lane = tid & 63;
    int wave = tid >> 6;
    int row  = blockIdx.x * 4 + wave;
    const float2* src = (const float2*)(F + (size_t)row * DIM) + lane;
    float2 x = *src;
    float s = x.x * x.x + x.y * x.y;
#pragma unroll
    for (int i = 1; i < 64; i <<= 1) s += __shfl_xor(s, i, 64);
    float scale = FEAT_SCALE / fmaxf(sqrtf(s), 1e-12f);
    __hip_bfloat162 h;
    h.x = __float2bfloat16(x.x * scale);
    h.y = __float2bfloat16(x.y * scale);
    ((__hip_bfloat162*)(G + (size_t)row * DIM))[lane] = h;
}

// ---------------------------------------------------------------- main tiles
// ATOM=false: pNum/pTot are [NTILES][N_ROWS] partial arrays, each slot written
//             exactly once (no atomics, no init needed).
// ATOM=true : pNum/pTot are [N_ROWS] accumulators (memset-0 first), atomicAdd.
template<bool ATOM>
__global__ __launch_bounds__(256, 2) void k_tiles(const __hip_bfloat16* __restrict__ G,
                                                  const int* __restrict__ lab,
                                                  float* __restrict__ pNum,
                                                  float* __restrict__ pTot) {
    int J = blockIdx.x, I = blockIdx.y;
    if (J < I) return;                 // upper triangle only
    bool diag = (I == J);

    __shared__ __align__(16) char lds[65536 + 4096];   // A(32K) B(32K) + reduce(4K)
    char* ldsA = lds;
    char* ldsB = diag ? lds : (lds + 32768);
    float* sR = (float*)(lds + 65536);          // [2(wc)][128] num, [2][128] tot
    float* sC = (float*)(lds + 65536 + 2048);   // [2(wr)][128] num, [2][128] tot

    int tid = threadIdx.x;

    // ---- stage tiles: 32KB contiguous each; pre-swizzled global source so the
    // XOR-swizzled ds_read_b128 below is bank-conflict-light (G4 / m173 pattern).
    {
        const char* gA = (const char*)G + (size_t)I * TILE * DIM * 2;
#pragma unroll
        for (int p = 0; p < 8; ++p) {
            int o = p * 4096 + tid * 16;
            int so = o ^ (((o >> 8) & 7) << 4);
            __builtin_amdgcn_global_load_lds((gas_ptr)(gA + so), (las_ptr)(ldsA + o), 16, 0, 0);
        }
        if (!diag) {
            const char* gB = (const char*)G + (size_t)J * TILE * DIM * 2;
#pragma unroll
            for (int p = 0; p < 8; ++p) {
                int o = p * 4096 + tid * 16;
                int so = o ^ (((o >> 8) & 7) << 4);
                __builtin_amdgcn_global_load_lds((gas_ptr)(gB + so), (las_ptr)(ldsB + o), 16, 0, 0);
            }
        }
    }
    __syncthreads();   // compiler drains vmcnt before barrier

    int lane = tid & 63, w = tid >> 6;
    int wr = w >> 1, wc = w & 1;          // 2x2 waves, 64x64 each
    int lr = lane & 15, lhi = lane >> 4;

    f32x4 acc[4][4];
#pragma unroll
    for (int m = 0; m < 4; ++m)
#pragma unroll
        for (int n = 0; n < 4; ++n) acc[m][n] = (f32x4){0.f, 0.f, 0.f, 0.f};

#pragma unroll
    for (int kk = 0; kk < 4; ++kk) {
        bf16x8 a[4], b[4];
#pragma unroll
        for (int m = 0; m < 4; ++m) {
            int row = wr * 64 + m * 16 + lr;
            int lin = row * 256 + kk * 64 + lhi * 16;
            a[m] = *(const bf16x8*)(ldsA + (lin ^ ((row & 7) << 4)));
        }
#pragma unroll
        for (int n = 0; n < 4; ++n) {
            int row = wc * 64 + n * 16 + lr;
            int lin = row * 256 + kk * 64 + lhi * 16;
            b[n] = *(const bf16x8*)(ldsB + (lin ^ ((row & 7) << 4)));
        }
#pragma unroll
        for (int m = 0; m < 4; ++m)
#pragma unroll
            for (int n = 0; n < 4; ++n)
                acc[m][n] = __builtin_amdgcn_mfma_f32_16x16x32_bf16(a[m], b[n], acc[m][n], 0, 0, 0);
    }

    // ---- fused epilogue: e = exp2(acc); accumulate per-lane row/col partials.
    int rowbase = I * TILE + wr * 64;
    int colbase = J * TILE + wc * 64;

    int labr[4][4];
#pragma unroll
    for (int m = 0; m < 4; ++m)
#pragma unroll
        for (int r = 0; r < 4; ++r) labr[m][r] = lab[rowbase + m * 16 + lhi * 4 + r];

    float rn[4][4], rt[4][4], cn[4], ct[4];
#pragma unroll
    for (int m = 0; m < 4; ++m)
#pragma unroll
        for (int r = 0; r < 4; ++r) { rn[m][r] = 0.f; rt[m][r] = 0.f; }
#pragma unroll
    for (int n = 0; n < 4; ++n) { cn[n] = 0.f; ct[n] = 0.f; }

#pragma unroll
    for (int n = 0; n < 4; ++n) {
        int col = colbase + n * 16 + lr;
        int labc = lab[col];
#pragma unroll
        for (int m = 0; m < 4; ++m) {
            int row0 = rowbase + m * 16 + lhi * 4;
#pragma unroll
            for (int r = 0; r < 4; ++r) {
                float e = __builtin_amdgcn_exp2f(acc[m][n][r]);
                float te = ((row0 + r) != col) ? e : 0.f;       // exclude diagonal
                float me = (labr[m][r] == labc) ? te : 0.f;     // positives
                rn[m][r] += me;  rt[m][r] += te;
                cn[n]    += me;  ct[n]    += te;
            }
        }
    }

    // ---- row side: reduce over the 16 lanes sharing a row (lr), to LDS.
#pragma unroll
    for (int m = 0; m < 4; ++m)
#pragma unroll
        for (int r = 0; r < 4; ++r) {
            float v1 = rn[m][r], v2 = rt[m][r];
#pragma unroll
            for (int s = 1; s < 16; s <<= 1) {
                v1 += __shfl_xor(v1, s, 64);
                v2 += __shfl_xor(v2, s, 64);
            }
            if (lr == 0) {
                int rowt = wr * 64 + m * 16 + lhi * 4 + r;
                sR[wc * 128 + rowt]       = v1;
                sR[256 + wc * 128 + rowt] = v2;
            }
        }
    // ---- col side: reduce over the 4 lane-groups sharing a col (lhi).
#pragma unroll
    for (int n = 0; n < 4; ++n) {
        float v1 = cn[n], v2 = ct[n];
        v1 += __shfl_xor(v1, 16, 64); v1 += __shfl_xor(v1, 32, 64);
        v2 += __shfl_xor(v2, 16, 64); v2 += __shfl_xor(v2, 32, 64);
        if (lhi == 0) {
            int colt = wc * 64 + n * 16 + lr;
            sC[wr * 128 + colt]       = v1;
            sC[256 + wr * 128 + colt] = v2;
        }
    }
    __syncthreads();

    // ---- combine the two contributing waves, write out.
    if (tid < 128) {
        float num = sR[tid] + sR[128 + tid];
        float tot = sR[256 + tid] + sR[384 + tid];
        int row = I * TILE + tid;
        if (ATOM) { atomicAdd(&pNum[row], num); atomicAdd(&pTot[row], tot); }
        else {
            pNum[(size_t)J * N_ROWS + row] = num;
            pTot[(size_t)J * N_ROWS + row] = tot;
        }
    } else if (!diag) {
        int c = tid - 128;
        float num = sC[c] + sC[128 + c];
        float tot = sC[256 + c] + sC[384 + c];
        int col = J * TILE + c;
        if (ATOM) { atomicAdd(&pNum[col], num); atomicAdd(&pTot[col], tot); }
        else {
            pNum[(size_t)I * N_ROWS + col] = num;
            pTot[(size_t)I * N_ROWS + col] = tot;
        }
    }
}

// ---------------------------------------------------------------- per-row loss
template<bool ATOM>
__global__ __launch_bounds__(256) void k_rowloss(const float* __restrict__ pNum,
                                                 const float* __restrict__ pTot,
                                                 float* __restrict__ losses) {
    int row = blockIdx.x * 256 + threadIdx.x;
    float num = 0.f, tot = 0.f;
    if (ATOM) {
        num = pNum[row]; tot = pTot[row];
    } else {
        for (int k = 0; k < NTILES; ++k) {
            num += pNum[(size_t)k * N_ROWS + row];
            tot += pTot[(size_t)k * N_ROWS + row];
        }
    }
    float ediag = expf(14.285714285714286f);       // exp(1/T), exact diagonal
    float denom = tot - num + ediag;
    losses[row] = -logf(num / denom + 1e-8f);
}

// ---------------------------------------------------------------- mean
__global__ __launch_bounds__(1024) void k_mean(const float* __restrict__ losses,
                                               float* __restrict__ out) {
    int tid = threadIdx.x;
    float s = 0.f;
    for (int i = tid; i < N_ROWS; i += 1024) s += losses[i];
#pragma unroll
    for (int i = 1; i < 64; i <<= 1) s += __shfl_xor(s, i, 64);
    __shared__ float red[16];
    if ((tid & 63) == 0) red[tid >> 6] = s;
    __syncthreads();
    if (tid < 16) {
        float v = red[tid];
#pragma unroll
        for (int i = 1; i < 16; i <<= 1) v += __shfl_xor(v, i, 64);
        if (tid == 0) out[0] = v / (float)N_ROWS;
    }
}

// ---------------------------------------------------------------- launcher
extern "C" void kernel_launch(void* const* d_in, const int* in_sizes, int n_in,
                              void* d_out, int out_size, void* d_ws, size_t ws_size,
                              hipStream_t stream) {
    const float* F  = (const float*)d_in[0];
    const int* lab  = (const int*)d_in[1];
    float* out      = (float*)d_out;
    char* ws        = (char*)d_ws;

    __hip_bfloat16* G = (__hip_bfloat16*)ws;                 // 4 MB
    float* losses = (float*)(ws + (4 << 20));                // 64 KB
    size_t offP = (4 << 20) + (64 << 10);

    k_normalize<<<N_ROWS / 4, 256, 0, stream>>>(F, G);

    bool partial = ws_size >= offP + ((size_t)16 << 20) + 1024;
    if (partial) {
        float* pNum = (float*)(ws + offP);                   // 8 MB
        float* pTot = (float*)(ws + offP + ((size_t)8 << 20)); // 8 MB
        k_tiles<false><<<dim3(NTILES, NTILES), 256, 0, stream>>>(G, lab, pNum, pTot);
        k_rowloss<false><<<N_ROWS / 256, 256, 0, stream>>>(pNum, pTot, losses);
    } else {
        float* rN = (float*)(ws + offP);                     // 64 KB
        float* rT = (float*)(ws + offP + (64 << 10));        // 64 KB
        hipMemsetAsync(rN, 0, 128 << 10, stream);
        k_tiles<true><<<dim3(NTILES, NTILES), 256, 0, stream>>>(G, lab, rN, rT);
        k_rowloss<true><<<N_ROWS / 256, 256, 0, stream>>>(rN, rT, losses);
    }
    k_mean<<<1, 1024, 0, stream>>>(losses, out);
}